// Round 1
// baseline (75.957 us; speedup 1.0000x reference)
//
#include <hip/hip_runtime.h>
#include <math.h>

// Problem constants
constexpr int B = 2, C = 16, H = 128, W = 128;
constexpr int KK = 19, PAD = 9;          // 19x19 per-pixel kernel, pad 9
constexpr int HP = H + 2 * PAD;          // 146  (padded x)
constexpr int YP = H + 2;                // 130  (padded y, pad 1 for conv2)
constexpr int XCH = HP * HP;             // 21316 floats per channel plane (x_pad)
constexpr int YCH = YP * YP;             // 16900 floats per channel plane (y_pad)
constexpr size_t XPAD_ELEMS = (size_t)B * C * XCH;   // 682,112
constexpr size_t YPAD_ELEMS = (size_t)B * C * YCH;   // 540,800

// ---------------------------------------------------------------------------
// Kernel 1: 3x3 conv (pad 1) + exact GELU, writes into padded x buffer
// one thread per output element (b, oc, h, w); 2048 blocks x 256
// ---------------------------------------------------------------------------
__global__ __launch_bounds__(256) void conv1_gelu(
    const float* __restrict__ in,   // [B,16,128,128]
    const float* __restrict__ w1,   // [16,16,3,3]
    const float* __restrict__ b1,   // [16]
    float* __restrict__ xpad)       // [B,16,146,146], pads pre-zeroed
{
    __shared__ float ws[16 * 16 * 9];
    for (int i = threadIdx.x; i < 16 * 16 * 9; i += 256) ws[i] = w1[i];
    __syncthreads();

    int t  = blockIdx.x * 256 + threadIdx.x;
    int w  = t & 127;
    int h  = (t >> 7) & 127;
    int oc = (t >> 14) & 15;
    int b  = t >> 18;

    float acc = b1[oc];
    const float* inb = in + (size_t)b * C * H * W;
    const float* wr  = ws + oc * 144;

    for (int dy = 0; dy < 3; ++dy) {
        int y = h + dy - 1;
        if ((unsigned)y >= (unsigned)H) continue;
        for (int dx = 0; dx < 3; ++dx) {
            int x = w + dx - 1;
            if ((unsigned)x >= (unsigned)W) continue;
            const float* ip = inb + y * W + x;
            const float* wp = wr + dy * 3 + dx;
            #pragma unroll
            for (int ic = 0; ic < 16; ++ic)
                acc += ip[ic * (H * W)] * wp[ic * 9];
        }
    }
    // exact (erf) GELU
    float g = 0.5f * acc * (1.0f + erff(acc * 0.70710678f));
    xpad[((size_t)(b * C + oc) * HP + (h + PAD)) * HP + (w + PAD)] = g;
}

// ---------------------------------------------------------------------------
// Kernel 2: per-pixel 19x19 convolution.
// out[b,c,h,w] = sum_{kh,kw} x[b,c,h+kh-9,w+kw-9] * kern[b,kh*19+kw,h,w]
// Block = 256 threads: 64 consecutive w-pixels x 4 channel-groups.
// Each thread accumulates 4 channels -> the 4 waves of a block read identical
// kern values (L1 broadcast), x reads fully coalesced. 512 blocks.
// ---------------------------------------------------------------------------
__global__ __launch_bounds__(256) void kpn19(
    const float* __restrict__ xpad,  // [B,16,146,146]
    const float* __restrict__ kern,  // [B,361,128,128]
    float* __restrict__ ypad)        // [B,16,130,130], pads pre-zeroed
{
    int blk = blockIdx.x;            // 512 blocks
    int w0  = (blk & 1) * 64;
    int h   = (blk >> 1) & 127;
    int b   = blk >> 8;

    int wl = threadIdx.x & 63;
    int cg = threadIdx.x >> 6;       // 0..3
    int w  = w0 + wl;
    int c0 = cg * 4;

    float acc0 = 0.f, acc1 = 0.f, acc2 = 0.f, acc3 = 0.f;

    const float* xb = xpad + (size_t)(b * C + c0) * XCH;           // channel c0
    const float* kp = kern + ((size_t)b * 361 * H + h) * W + w;    // p = 0

    for (int kh = 0; kh < KK; ++kh) {
        const float* xr = xb + (h + kh) * HP + w;   // + kw walks columns
        #pragma unroll
        for (int kw = 0; kw < KK; ++kw) {
            float k  = *kp;
            float x0 = xr[kw];
            float x1 = xr[kw + XCH];
            float x2 = xr[kw + 2 * XCH];
            float x3 = xr[kw + 3 * XCH];
            acc0 = fmaf(x0, k, acc0);
            acc1 = fmaf(x1, k, acc1);
            acc2 = fmaf(x2, k, acc2);
            acc3 = fmaf(x3, k, acc3);
            kp += H * W;             // next p
        }
    }

    size_t yb = ((size_t)(b * C + c0) * YP + (h + 1)) * YP + (w + 1);
    ypad[yb]            = acc0;
    ypad[yb + YCH]      = acc1;
    ypad[yb + 2 * YCH]  = acc2;
    ypad[yb + 3 * YCH]  = acc3;
}

// ---------------------------------------------------------------------------
// Kernel 3: 3x3 conv (pad 1) + sigmoid, reads padded y, writes d_out
// ---------------------------------------------------------------------------
__global__ __launch_bounds__(256) void conv2_sig(
    const float* __restrict__ ypad,  // [B,16,130,130]
    const float* __restrict__ w2,    // [16,16,3,3]
    const float* __restrict__ b2,    // [16]
    float* __restrict__ out)         // [B,16,128,128]
{
    __shared__ float ws[16 * 16 * 9];
    for (int i = threadIdx.x; i < 16 * 16 * 9; i += 256) ws[i] = w2[i];
    __syncthreads();

    int t  = blockIdx.x * 256 + threadIdx.x;
    int w  = t & 127;
    int h  = (t >> 7) & 127;
    int oc = (t >> 14) & 15;
    int b  = t >> 18;

    float acc = b2[oc];
    const float* yb = ypad + (size_t)b * C * YCH;
    const float* wr = ws + oc * 144;

    #pragma unroll
    for (int ic = 0; ic < 16; ++ic) {
        const float* yc = yb + ic * YCH + h * YP + w;   // (h+dy)*YP + (w+dx), dy,dx in 0..2
        const float* wp = wr + ic * 9;
        #pragma unroll
        for (int dy = 0; dy < 3; ++dy) {
            #pragma unroll
            for (int dx = 0; dx < 3; ++dx)
                acc = fmaf(yc[dy * YP + dx], wp[dy * 3 + dx], acc);
        }
    }
    out[t] = 1.0f / (1.0f + expf(-acc));
}

// ---------------------------------------------------------------------------
extern "C" void kernel_launch(void* const* d_in, const int* in_sizes, int n_in,
                              void* d_out, int out_size, void* d_ws, size_t ws_size,
                              hipStream_t stream)
{
    const float* input  = (const float*)d_in[0];  // [2,16,128,128]
    const float* kernel = (const float*)d_in[1];  // [2,361,128,128]
    const float* w1     = (const float*)d_in[2];
    const float* b1     = (const float*)d_in[3];
    const float* w2     = (const float*)d_in[4];
    const float* b2     = (const float*)d_in[5];
    float* out = (float*)d_out;

    float* xpad = (float*)d_ws;
    float* ypad = xpad + XPAD_ELEMS;

    // zero pads (and everything else in the staging buffers) each call
    hipMemsetAsync(d_ws, 0, (XPAD_ELEMS + YPAD_ELEMS) * sizeof(float), stream);

    int n1 = B * C * H * W;                       // 524288
    conv1_gelu<<<n1 / 256, 256, 0, stream>>>(input, w1, b1, xpad);

    kpn19<<<(B * H * W) / 64, 256, 0, stream>>>(xpad, kernel, ypad);

    conv2_sig<<<n1 / 256, 256, 0, stream>>>(ypad, w2, b2, out);
}